// Round 2
// baseline (2487.243 us; speedup 1.0000x reference)
//
#include <hip/hip_runtime.h>
#include <stdint.h>
#include <math.h>

#define N_ROWS 8192
#define N_TOK  8192
#define N_DIM  512
#define N_SAMP 10

// ---------------- JAX threefry2x32 (exact) ----------------
__host__ __device__ __forceinline__ void tf2x32(uint32_t ks0, uint32_t ks1,
                                                uint32_t& x0, uint32_t& x1) {
  uint32_t ks2 = ks0 ^ ks1 ^ 0x1BD11BDAu;
  x0 += ks0; x1 += ks1;
#define TF_ROUND(r) { x0 += x1; x1 = (x1 << (r)) | (x1 >> (32 - (r))); x1 ^= x0; }
  TF_ROUND(13) TF_ROUND(15) TF_ROUND(26) TF_ROUND(6)
  x0 += ks1; x1 += ks2 + 1u;
  TF_ROUND(17) TF_ROUND(29) TF_ROUND(16) TF_ROUND(24)
  x0 += ks2; x1 += ks0 + 2u;
  TF_ROUND(13) TF_ROUND(15) TF_ROUND(26) TF_ROUND(6)
  x0 += ks0; x1 += ks1 + 3u;
  TF_ROUND(17) TF_ROUND(29) TF_ROUND(16) TF_ROUND(24)
  x0 += ks1; x1 += ks2 + 4u;
  TF_ROUND(13) TF_ROUND(15) TF_ROUND(26) TF_ROUND(6)
  x0 += ks2; x1 += ks0 + 5u;
#undef TF_ROUND
}

// ---------------- row sum-of-squares ----------------
__global__ __launch_bounds__(256) void rownorm_kernel(const float* __restrict__ M,
                                                      float* __restrict__ out) {
  int lane = threadIdx.x & 63;
  int row = (int)((blockIdx.x * blockDim.x + threadIdx.x) >> 6);
  const float* p = M + (size_t)row * N_DIM;
  float acc = 0.f;
#pragma unroll
  for (int d = 0; d < N_DIM; d += 64) {
    float v = p[d + lane];
    acc = fmaf(v, v, acc);
  }
#pragma unroll
  for (int off = 32; off; off >>= 1) acc += __shfl_xor(acc, off, 64);
  if (lane == 0) out[row] = acc;
}

__global__ __launch_bounds__(256) void init_state_kernel(float* __restrict__ rmax,
                                                         int* __restrict__ ridx) {
  int i = blockIdx.x * 256 + threadIdx.x;
  if (i < N_ROWS * N_SAMP) { rmax[i] = -INFINITY; ridx[i] = 0; }
}

// ---------------- fp32 NT GEMM: dots[i][kk] = dot(x_i, e_{ks+kk}) ----------------
__global__ __launch_bounds__(256) void gemm_nt_kernel(const float* __restrict__ A,
                                                      const float* __restrict__ B,
                                                      float* __restrict__ C,
                                                      int ks, int KC) {
  __shared__ __align__(16) float As[32][68];
  __shared__ __align__(16) float Bs[32][68];
  int tid = threadIdx.x;
  int row0 = blockIdx.y * 64;
  int colB0 = blockIdx.x * 64 + ks;
  int tx = tid & 15, ty = tid >> 4;
  float acc[4][4] = {};
  for (int d0 = 0; d0 < N_DIM; d0 += 32) {
#pragma unroll
    for (int r = 0; r < 2; ++r) {
      int c = tid + 256 * r;       // 0..511
      int m = c >> 3;              // tile row/col 0..63
      int dv = (c & 7) << 2;       // d offset 0..28
      const float4 va = *(const float4*)(A + (size_t)(row0 + m) * N_DIM + d0 + dv);
      As[dv + 0][m] = va.x; As[dv + 1][m] = va.y;
      As[dv + 2][m] = va.z; As[dv + 3][m] = va.w;
      const float4 vb = *(const float4*)(B + (size_t)(colB0 + m) * N_DIM + d0 + dv);
      Bs[dv + 0][m] = vb.x; Bs[dv + 1][m] = vb.y;
      Bs[dv + 2][m] = vb.z; Bs[dv + 3][m] = vb.w;
    }
    __syncthreads();
#pragma unroll
    for (int dd = 0; dd < 32; ++dd) {
      float4 a4 = *(const float4*)&As[dd][ty << 2];
      float4 b4 = *(const float4*)&Bs[dd][tx << 2];
      float av[4] = {a4.x, a4.y, a4.z, a4.w};
      float bv[4] = {b4.x, b4.y, b4.z, b4.w};
#pragma unroll
      for (int i = 0; i < 4; ++i)
#pragma unroll
        for (int j = 0; j < 4; ++j)
          acc[i][j] = fmaf(av[i], bv[j], acc[i][j]);
    }
    __syncthreads();
  }
  int colC0 = blockIdx.x * 64;
#pragma unroll
  for (int i = 0; i < 4; ++i) {
    float4 v = make_float4(acc[i][0], acc[i][1], acc[i][2], acc[i][3]);
    *(float4*)(C + (size_t)(row0 + (ty << 2) + i) * KC + colC0 + (tx << 2)) = v;
  }
}

// ---------------- gumbel argmax sampling (partitionable threefry) ----------------
__global__ __launch_bounds__(256) void sample_kernel(const float* __restrict__ dots,
                                                     const float* __restrict__ xx,
                                                     const float* __restrict__ ee,
                                                     float* __restrict__ rmax,
                                                     int* __restrict__ ridx,
                                                     int ks, int KC,
                                                     uint32_t k0, uint32_t k1) {
  int lane = threadIdx.x & 63;
  int row = (int)((blockIdx.x * blockDim.x + threadIdx.x) >> 6);
  float xxi = xx[row];
  float bmax[N_SAMP];
  int bidx[N_SAMP];
#pragma unroll
  for (int s = 0; s < N_SAMP; ++s) { bmax[s] = -INFINITY; bidx[s] = 0; }
  const float inv_nt = 1.f / 8192.f;
  const float tiny = 1.1754943508222875e-38f;
  uint32_t rowbase = (uint32_t)row * (uint32_t)N_SAMP;  // i*10

  for (int kk = lane; kk < KC; kk += 64) {
    int k = ks + kk;
    float dot = dots[(size_t)row * KC + kk];
    float t = xxi + ee[k];
    float L = (2.f * dot - t) * inv_nt;   // == -((xx+ee) - 2*dot)/8192, bit-identical
#pragma unroll
    for (int s = 0; s < N_SAMP; ++s) {
      uint32_t c = (rowbase + (uint32_t)s) * 8192u + (uint32_t)k;
      uint32_t x0 = 0u, x1 = c;
      tf2x32(k0, k1, x0, x1);
      uint32_t bits = x0 ^ x1;  // partitionable-mode 32-bit combine
      float u = __uint_as_float(0x3f800000u | (bits >> 9)) - 1.0f;
      u = u + tiny;
      u = fmaxf(tiny, u);
      float g = -logf(-logf(u));
      float v = g + L;
      if (v > bmax[s]) { bmax[s] = v; bidx[s] = k; }
    }
  }
  // wave arg-reduce: max value, ties -> smallest index (matches jnp.argmax)
#pragma unroll
  for (int s = 0; s < N_SAMP; ++s) {
    float v = bmax[s];
    int id = bidx[s];
#pragma unroll
    for (int off = 32; off; off >>= 1) {
      float ov = __shfl_xor(v, off, 64);
      int oi = __shfl_xor(id, off, 64);
      if (ov > v || (ov == v && oi < id)) { v = ov; id = oi; }
    }
    if (lane == 0) {
      size_t p = (size_t)row * N_SAMP + s;
      if (v > rmax[p]) { rmax[p] = v; ridx[p] = id; }  // strips ascend in k
    }
  }
}

// ---------------- gather + mean + straight-through, write both outputs ----------------
// NOTE (fallback layout): ridx may alias the outs region. Each wave reads all 10
// indices into registers BEFORE the lane<10 store; wave64 lockstep makes that safe.
__global__ __launch_bounds__(256) void gather_kernel(const float* __restrict__ emb,
                                                     const int* __restrict__ ridx,
                                                     const float* __restrict__ x,
                                                     float* __restrict__ outq,
                                                     float* __restrict__ outs) {
  int lane = threadIdx.x & 63;
  int row = (int)((blockIdx.x * blockDim.x + threadIdx.x) >> 6);
  int idx[N_SAMP];
#pragma unroll
  for (int s = 0; s < N_SAMP; ++s) idx[s] = ridx[row * N_SAMP + s];
  if (lane < N_SAMP) outs[row * N_SAMP + lane] = (float)idx[lane];
#pragma unroll
  for (int c = lane; c < N_DIM; c += 64) {
    float sum = 0.f;
#pragma unroll
    for (int s = 0; s < N_SAMP; ++s) sum += emb[(size_t)idx[s] * N_DIM + c];
    float qe = sum / 10.0f;
    float xv = x[(size_t)row * N_DIM + c];
    outq[(size_t)row * N_DIM + c] = xv + (qe - xv);  // straight-through, as JAX computes
  }
}

extern "C" void kernel_launch(void* const* d_in, const int* in_sizes, int n_in,
                              void* d_out, int out_size, void* d_ws, size_t ws_size,
                              hipStream_t stream) {
  const float* x = (const float*)d_in[0];     // (4,2048,512) -> 8192x512
  const float* emb = (const float*)d_in[1];   // 8192x512
  float* out_q = (float*)d_out;                       // 8192*512 floats
  float* out_s = out_q + (size_t)N_ROWS * N_DIM;      // 8192*10 sample indices as float

  const size_t fixed_f = (size_t)N_ROWS + N_TOK + 2 * (size_t)N_ROWS * N_SAMP; // 180224 floats
  const size_t out_f = (size_t)N_ROWS * N_DIM + (size_t)N_ROWS * N_SAMP;       // 4276224 floats

  float *xx, *ee, *rmax, *dots;
  int* ridx;
  int KC = 0;

  // Case A: everything fits in d_ws.
  for (int c = 8192; c >= 64; c >>= 1) {
    if ((fixed_f + (size_t)N_ROWS * c) * 4 <= ws_size) { KC = c; break; }
  }
  if (KC) {
    xx = (float*)d_ws;
    ee = xx + N_ROWS;
    rmax = ee + N_TOK;
    ridx = (int*)(rmax + (size_t)N_ROWS * N_SAMP);
    dots = (float*)(ridx + (size_t)N_ROWS * N_SAMP);
  } else if (fixed_f * 4 <= ws_size) {
    // Case B: small state in ws; dots strip lives in out_q (dead until gather).
    KC = 512;  // 8192*512 floats == exactly the out_q region
    xx = (float*)d_ws;
    ee = xx + N_ROWS;
    rmax = ee + N_TOK;
    ridx = (int*)(rmax + (size_t)N_ROWS * N_SAMP);
    dots = out_q;
  } else {
    // Case C: everything inside d_out. dots = out_q[0 .. 8192*256), small state
    // packed in the top fixed_f floats of d_out (exactly fits; all dead before
    // the regions are overwritten by the final gather — see gather_kernel note).
    KC = 256;
    dots = out_q;
    float* tail = out_q + (out_f - fixed_f);
    xx = tail;
    ee = xx + N_ROWS;
    rmax = ee + N_TOK;
    ridx = (int*)(rmax + (size_t)N_ROWS * N_SAMP);
  }

  // skey = fold_in(key(0), 1) = threefry2x32(ks=(0,0), x=(0,1))
  uint32_t s0 = 0u, s1 = 1u;
  tf2x32(0u, 0u, s0, s1);

  rownorm_kernel<<<2048, 256, 0, stream>>>(x, xx);
  rownorm_kernel<<<2048, 256, 0, stream>>>(emb, ee);
  init_state_kernel<<<(N_ROWS * N_SAMP + 255) / 256, 256, 0, stream>>>(rmax, ridx);

  for (int ks = 0; ks < N_TOK; ks += KC) {
    gemm_nt_kernel<<<dim3(KC / 64, N_ROWS / 64), 256, 0, stream>>>(x, emb, dots, ks, KC);
    sample_kernel<<<2048, 256, 0, stream>>>(dots, xx, ee, rmax, ridx, ks, KC, s0, s1);
  }

  gather_kernel<<<2048, 256, 0, stream>>>(emb, ridx, x, out_q, out_s);
}

// Round 5
// 1876.176 us; speedup vs baseline: 1.3257x; 1.3257x over previous
//
#include <hip/hip_runtime.h>
#include <stdint.h>
#include <math.h>

#define N_ROWS 8192
#define N_TOK  8192
#define N_DIM  512
#define N_SAMP 10
#define GK     1536   // 3 * 512, bf16x2 split zones

typedef __attribute__((ext_vector_type(8))) short bf16x8_t;  // 8 bf16 in 4 VGPRs
typedef __attribute__((ext_vector_type(4))) float f32x4_t;

// ---------------- JAX threefry2x32 (exact) ----------------
__host__ __device__ __forceinline__ void tf2x32(uint32_t ks0, uint32_t ks1,
                                                uint32_t& x0, uint32_t& x1) {
  uint32_t ks2 = ks0 ^ ks1 ^ 0x1BD11BDAu;
  x0 += ks0; x1 += ks1;
#define TF_ROUND(r) { x0 += x1; x1 = (x1 << (r)) | (x1 >> (32 - (r))); x1 ^= x0; }
  TF_ROUND(13) TF_ROUND(15) TF_ROUND(26) TF_ROUND(6)
  x0 += ks1; x1 += ks2 + 1u;
  TF_ROUND(17) TF_ROUND(29) TF_ROUND(16) TF_ROUND(24)
  x0 += ks2; x1 += ks0 + 2u;
  TF_ROUND(13) TF_ROUND(15) TF_ROUND(26) TF_ROUND(6)
  x0 += ks0; x1 += ks1 + 3u;
  TF_ROUND(17) TF_ROUND(29) TF_ROUND(16) TF_ROUND(24)
  x0 += ks1; x1 += ks2 + 4u;
  TF_ROUND(13) TF_ROUND(15) TF_ROUND(26) TF_ROUND(6)
  x0 += ks2; x1 += ks0 + 5u;
#undef TF_ROUND
}

__device__ __forceinline__ unsigned short f2bf_rne(float f) {
  uint32_t u = __float_as_uint(f);
  uint32_t r = (u + 0x7fffu + ((u >> 16) & 1u)) >> 16;
  return (unsigned short)r;
}
__device__ __forceinline__ float bf2f(unsigned short h) {
  return __uint_as_float((uint32_t)h << 16);
}

// ---------------- row sum-of-squares ----------------
__global__ __launch_bounds__(256) void rownorm_kernel(const float* __restrict__ M,
                                                      float* __restrict__ out) {
  int lane = threadIdx.x & 63;
  int row = (int)((blockIdx.x * blockDim.x + threadIdx.x) >> 6);
  const float* p = M + (size_t)row * N_DIM;
  float acc = 0.f;
#pragma unroll
  for (int d = 0; d < N_DIM; d += 64) {
    float v = p[d + lane];
    acc = fmaf(v, v, acc);
  }
#pragma unroll
  for (int off = 32; off; off >>= 1) acc += __shfl_xor(acc, off, 64);
  if (lane == 0) out[row] = acc;
}

__global__ __launch_bounds__(256) void init_state_kernel(float* __restrict__ rmax,
                                                         int* __restrict__ ridx) {
  int i = blockIdx.x * 256 + threadIdx.x;
  if (i < N_ROWS * N_SAMP) { rmax[i] = -INFINITY; ridx[i] = 0; }
}

// ---------------- bf16x2 split: fp32 (8192x512) -> bf16 (8192x1536) ----------------
// mode 0 (A/x):   zones [hi | lo | hi]
// mode 1 (B/emb): zones [hi | hi | lo]
__global__ __launch_bounds__(256) void split_kernel(const float* __restrict__ src,
                                                    unsigned short* __restrict__ dst,
                                                    int mode) {
  int t = blockIdx.x * 256 + threadIdx.x;       // N_ROWS * 128 threads
  int row = t >> 7;
  int c = (t & 127) << 2;
  float4 v = *(const float4*)(src + (size_t)row * N_DIM + c);
  ushort4 hi, lo;
  hi.x = f2bf_rne(v.x); lo.x = f2bf_rne(v.x - bf2f(hi.x));
  hi.y = f2bf_rne(v.y); lo.y = f2bf_rne(v.y - bf2f(hi.y));
  hi.z = f2bf_rne(v.z); lo.z = f2bf_rne(v.z - bf2f(hi.z));
  hi.w = f2bf_rne(v.w); lo.w = f2bf_rne(v.w - bf2f(hi.w));
  unsigned short* base = dst + (size_t)row * GK;
  *(ushort4*)(base + c) = hi;
  if (mode == 0) {
    *(ushort4*)(base + 512 + c) = lo;
    *(ushort4*)(base + 1024 + c) = hi;
  } else {
    *(ushort4*)(base + 512 + c) = hi;
    *(ushort4*)(base + 1024 + c) = lo;
  }
}

// ---------------- bf16 MFMA NT GEMM (sync staging, 16B chunks) ----------------
// C[i][j] = sum_k A2[row0+i][k] * B2[bcol0+j][k], 128x128 tile, BK=32
__global__ __launch_bounds__(256) void gemm_bf16_kernel(const unsigned short* __restrict__ A2,
                                                        const unsigned short* __restrict__ B2,
                                                        float* __restrict__ C,
                                                        int ks, int KC) {
  __shared__ __align__(16) unsigned short As[128 * 32];
  __shared__ __align__(16) unsigned short Bs[128 * 32];
  int tid = threadIdx.x;
  int w = tid >> 6, l = tid & 63;
  int row0 = blockIdx.y * 128;
  int col0 = blockIdx.x * 128;      // within-strip C column
  int bcol0 = ks + col0;            // global token row of B2
  int wm = (w & 1) * 64, wn = (w >> 1) * 64;
  int quad = l >> 4, r15 = l & 15;

  f32x4_t acc[4][4];
#pragma unroll
  for (int i = 0; i < 4; ++i)
#pragma unroll
    for (int j = 0; j < 4; ++j) acc[i][j] = (f32x4_t){0.f, 0.f, 0.f, 0.f};

  // 512 x 16B chunks per 128x32 tile; each thread stages chunks c0 and c0+256.
  // BUGFIX vs r4: stage with uint4 (16 B), not ushort4 (8 B) — chunk math is 16B.
  int c0 = w * 64 + l;
  int c1 = c0 + 256;
  const size_t ga0 = (size_t)(row0 + (c0 >> 2)) * GK + (c0 & 3) * 8;
  const size_t ga1 = (size_t)(row0 + (c1 >> 2)) * GK + (c1 & 3) * 8;
  const size_t gb0 = (size_t)(bcol0 + (c0 >> 2)) * GK + (c0 & 3) * 8;
  const size_t gb1 = (size_t)(bcol0 + (c1 >> 2)) * GK + (c1 & 3) * 8;

  for (int k0 = 0; k0 < GK; k0 += 32) {
    uint4 ra0 = *(const uint4*)(A2 + ga0 + k0);
    uint4 ra1 = *(const uint4*)(A2 + ga1 + k0);
    uint4 rb0 = *(const uint4*)(B2 + gb0 + k0);
    uint4 rb1 = *(const uint4*)(B2 + gb1 + k0);
    __syncthreads();   // prior iteration's ds_reads complete before overwrite
    *(uint4*)(As + c0 * 8) = ra0;
    *(uint4*)(As + c1 * 8) = ra1;
    *(uint4*)(Bs + c0 * 8) = rb0;
    *(uint4*)(Bs + c1 * 8) = rb1;
    __syncthreads();

    bf16x8_t af[4], bf[4];
#pragma unroll
    for (int i = 0; i < 4; ++i)
      af[i] = *(const bf16x8_t*)&As[(wm + i * 16 + r15) * 32 + quad * 8];
#pragma unroll
    for (int j = 0; j < 4; ++j)
      bf[j] = *(const bf16x8_t*)&Bs[(wn + j * 16 + r15) * 32 + quad * 8];
#pragma unroll
    for (int i = 0; i < 4; ++i)
#pragma unroll
      for (int j = 0; j < 4; ++j)
        acc[i][j] = __builtin_amdgcn_mfma_f32_16x16x32_bf16(af[i], bf[j], acc[i][j], 0, 0, 0);
  }

  // epilogue: C/D layout col=lane&15, row=(lane>>4)*4+reg
#pragma unroll
  for (int i = 0; i < 4; ++i)
#pragma unroll
    for (int j = 0; j < 4; ++j) {
#pragma unroll
      for (int r = 0; r < 4; ++r) {
        int grow = row0 + wm + i * 16 + quad * 4 + r;
        int gcol = col0 + wn + j * 16 + r15;
        C[(size_t)grow * KC + gcol] = acc[i][j][r];
      }
    }
}

// ---------------- fp32 NT GEMM (fallback path, proven) ----------------
__global__ __launch_bounds__(256) void gemm_nt_kernel(const float* __restrict__ A,
                                                      const float* __restrict__ B,
                                                      float* __restrict__ C,
                                                      int ks, int KC) {
  __shared__ __align__(16) float Asf[32][68];
  __shared__ __align__(16) float Bsf[32][68];
  int tid = threadIdx.x;
  int row0 = blockIdx.y * 64;
  int colB0 = blockIdx.x * 64 + ks;
  int tx = tid & 15, ty = tid >> 4;
  float acc[4][4] = {};
  for (int d0 = 0; d0 < N_DIM; d0 += 32) {
#pragma unroll
    for (int r = 0; r < 2; ++r) {
      int c = tid + 256 * r;
      int m = c >> 3;
      int dv = (c & 7) << 2;
      const float4 va = *(const float4*)(A + (size_t)(row0 + m) * N_DIM + d0 + dv);
      Asf[dv + 0][m] = va.x; Asf[dv + 1][m] = va.y;
      Asf[dv + 2][m] = va.z; Asf[dv + 3][m] = va.w;
      const float4 vb = *(const float4*)(B + (size_t)(colB0 + m) * N_DIM + d0 + dv);
      Bsf[dv + 0][m] = vb.x; Bsf[dv + 1][m] = vb.y;
      Bsf[dv + 2][m] = vb.z; Bsf[dv + 3][m] = vb.w;
    }
    __syncthreads();
#pragma unroll
    for (int dd = 0; dd < 32; ++dd) {
      float4 a4 = *(const float4*)&Asf[dd][ty << 2];
      float4 b4 = *(const float4*)&Bsf[dd][tx << 2];
      float av[4] = {a4.x, a4.y, a4.z, a4.w};
      float bv[4] = {b4.x, b4.y, b4.z, b4.w};
#pragma unroll
      for (int i = 0; i < 4; ++i)
#pragma unroll
        for (int j = 0; j < 4; ++j)
          acc[i][j] = fmaf(av[i], bv[j], acc[i][j]);
    }
    __syncthreads();
  }
  int colC0 = blockIdx.x * 64;
#pragma unroll
  for (int i = 0; i < 4; ++i) {
    float4 v = make_float4(acc[i][0], acc[i][1], acc[i][2], acc[i][3]);
    *(float4*)(C + (size_t)(row0 + (ty << 2) + i) * KC + colC0 + (tx << 2)) = v;
  }
}

// ---------------- gumbel argmax sampling (partitionable threefry) ----------------
__global__ __launch_bounds__(256) void sample_kernel(const float* __restrict__ dots,
                                                     const float* __restrict__ xx,
                                                     const float* __restrict__ ee,
                                                     float* __restrict__ rmax,
                                                     int* __restrict__ ridx,
                                                     int ks, int KC,
                                                     uint32_t k0, uint32_t k1) {
  int lane = threadIdx.x & 63;
  int row = (int)((blockIdx.x * blockDim.x + threadIdx.x) >> 6);
  float xxi = xx[row];
  float bmax[N_SAMP];
  int bidx[N_SAMP];
#pragma unroll
  for (int s = 0; s < N_SAMP; ++s) { bmax[s] = -INFINITY; bidx[s] = 0; }
  const float inv_nt = 1.f / 8192.f;
  const float tiny = 1.1754943508222875e-38f;
  uint32_t rowbase = (uint32_t)row * (uint32_t)N_SAMP;

  for (int kk = lane; kk < KC; kk += 64) {
    int k = ks + kk;
    float dot = dots[(size_t)row * KC + kk];
    float t = xxi + ee[k];
    float L = (2.f * dot - t) * inv_nt;
#pragma unroll
    for (int s = 0; s < N_SAMP; ++s) {
      uint32_t c = (rowbase + (uint32_t)s) * 8192u + (uint32_t)k;
      uint32_t x0 = 0u, x1 = c;
      tf2x32(k0, k1, x0, x1);
      uint32_t bits = x0 ^ x1;
      float u = __uint_as_float(0x3f800000u | (bits >> 9)) - 1.0f;
      u = u + tiny;
      u = fmaxf(tiny, u);
      float g = -logf(-logf(u));
      float v = g + L;
      if (v > bmax[s]) { bmax[s] = v; bidx[s] = k; }
    }
  }
#pragma unroll
  for (int s = 0; s < N_SAMP; ++s) {
    float v = bmax[s];
    int id = bidx[s];
#pragma unroll
    for (int off = 32; off; off >>= 1) {
      float ov = __shfl_xor(v, off, 64);
      int oi = __shfl_xor(id, off, 64);
      if (ov > v || (ov == v && oi < id)) { v = ov; id = oi; }
    }
    if (lane == 0) {
      size_t p = (size_t)row * N_SAMP + s;
      if (v > rmax[p]) { rmax[p] = v; ridx[p] = id; }
    }
  }
}

// ---------------- gather + mean + straight-through ----------------
__global__ __launch_bounds__(256) void gather_kernel(const float* __restrict__ emb,
                                                     const int* __restrict__ ridx,
                                                     const float* __restrict__ x,
                                                     float* __restrict__ outq,
                                                     float* __restrict__ outs) {
  int lane = threadIdx.x & 63;
  int row = (int)((blockIdx.x * blockDim.x + threadIdx.x) >> 6);
  int idx[N_SAMP];
#pragma unroll
  for (int s = 0; s < N_SAMP; ++s) idx[s] = ridx[row * N_SAMP + s];
  if (lane < N_SAMP) outs[row * N_SAMP + lane] = (float)idx[lane];
#pragma unroll
  for (int c = lane; c < N_DIM; c += 64) {
    float sum = 0.f;
#pragma unroll
    for (int s = 0; s < N_SAMP; ++s) sum += emb[(size_t)idx[s] * N_DIM + c];
    float qe = sum / 10.0f;
    float xv = x[(size_t)row * N_DIM + c];
    outq[(size_t)row * N_DIM + c] = xv + (qe - xv);
  }
}

extern "C" void kernel_launch(void* const* d_in, const int* in_sizes, int n_in,
                              void* d_out, int out_size, void* d_ws, size_t ws_size,
                              hipStream_t stream) {
  const float* x = (const float*)d_in[0];
  const float* emb = (const float*)d_in[1];
  float* out_q = (float*)d_out;
  float* out_s = out_q + (size_t)N_ROWS * N_DIM;

  const size_t fixed_f = (size_t)N_ROWS + N_TOK + 2 * (size_t)N_ROWS * N_SAMP;  // 180224 floats
  const size_t out_f = (size_t)N_ROWS * N_DIM + (size_t)N_ROWS * N_SAMP;
  const size_t split_u = (size_t)N_ROWS * GK;  // ushorts per split matrix

  // skey = fold_in(key(0), 1)
  uint32_t s0 = 0u, s1 = 1u;
  tf2x32(0u, 0u, s0, s1);

  // ---- preferred path: bf16x2 MFMA GEMM, needs fixed + 2 splits + dots strip in ws ----
  int KC = 0;
  for (int c = 8192; c >= 128; c >>= 1) {
    size_t need = fixed_f * 4 + 2 * split_u * 2 + (size_t)N_ROWS * c * 4;
    if (need <= ws_size) { KC = c; break; }
  }

  if (KC) {
    float* xx = (float*)d_ws;
    float* ee = xx + N_ROWS;
    float* rmax = ee + N_TOK;
    int* ridx = (int*)(rmax + (size_t)N_ROWS * N_SAMP);
    unsigned short* A2 = (unsigned short*)(ridx + (size_t)N_ROWS * N_SAMP);
    unsigned short* B2 = A2 + split_u;
    float* dots = (float*)(B2 + split_u);

    rownorm_kernel<<<2048, 256, 0, stream>>>(x, xx);
    rownorm_kernel<<<2048, 256, 0, stream>>>(emb, ee);
    init_state_kernel<<<(N_ROWS * N_SAMP + 255) / 256, 256, 0, stream>>>(rmax, ridx);
    split_kernel<<<N_ROWS * 128 / 256, 256, 0, stream>>>(x, A2, 0);
    split_kernel<<<N_ROWS * 128 / 256, 256, 0, stream>>>(emb, B2, 1);

    for (int ks = 0; ks < N_TOK; ks += KC) {
      gemm_bf16_kernel<<<dim3(KC / 128, N_ROWS / 128), 256, 0, stream>>>(A2, B2, dots, ks, KC);
      sample_kernel<<<2048, 256, 0, stream>>>(dots, xx, ee, rmax, ridx, ks, KC, s0, s1);
    }
    gather_kernel<<<2048, 256, 0, stream>>>(emb, ridx, x, out_q, out_s);
    return;
  }

  // ---- fallback: proven fp32 path with adaptive placement ----
  float *xx, *ee, *rmax, *dots;
  int* ridx;
  KC = 0;
  for (int c = 8192; c >= 64; c >>= 1) {
    if ((fixed_f + (size_t)N_ROWS * c) * 4 <= ws_size) { KC = c; break; }
  }
  if (KC) {
    xx = (float*)d_ws;
    ee = xx + N_ROWS;
    rmax = ee + N_TOK;
    ridx = (int*)(rmax + (size_t)N_ROWS * N_SAMP);
    dots = (float*)(ridx + (size_t)N_ROWS * N_SAMP);
  } else if (fixed_f * 4 <= ws_size) {
    KC = 512;
    xx = (float*)d_ws;
    ee = xx + N_ROWS;
    rmax = ee + N_TOK;
    ridx = (int*)(rmax + (size_t)N_ROWS * N_SAMP);
    dots = out_q;
  } else {
    KC = 256;
    dots = out_q;
    float* tail = out_q + (out_f - fixed_f);
    xx = tail;
    ee = xx + N_ROWS;
    rmax = ee + N_TOK;
    ridx = (int*)(rmax + (size_t)N_ROWS * N_SAMP);
  }

  rownorm_kernel<<<2048, 256, 0, stream>>>(x, xx);
  rownorm_kernel<<<2048, 256, 0, stream>>>(emb, ee);
  init_state_kernel<<<(N_ROWS * N_SAMP + 255) / 256, 256, 0, stream>>>(rmax, ridx);
  for (int ks = 0; ks < N_TOK; ks += KC) {
    gemm_nt_kernel<<<dim3(KC / 64, N_ROWS / 64), 256, 0, stream>>>(x, emb, dots, ks, KC);
    sample_kernel<<<2048, 256, 0, stream>>>(dots, xx, ee, rmax, ridx, ks, KC, s0, s1);
  }
  gather_kernel<<<2048, 256, 0, stream>>>(emb, ridx, x, out_q, out_s);
}

// Round 6
// 1723.558 us; speedup vs baseline: 1.4431x; 1.0885x over previous
//
#include <hip/hip_runtime.h>
#include <stdint.h>
#include <math.h>

#define N_ROWS 8192
#define N_TOK  8192
#define N_DIM  512
#define N_SAMP 10
#define GK     1536   // 3 * 512, bf16x2 split zones

typedef __attribute__((ext_vector_type(8))) short bf16x8_t;  // 8 bf16 in 4 VGPRs
typedef __attribute__((ext_vector_type(4))) float f32x4_t;

// ---------------- JAX threefry2x32 (exact) ----------------
__host__ __device__ __forceinline__ void tf2x32(uint32_t ks0, uint32_t ks1,
                                                uint32_t& x0, uint32_t& x1) {
  uint32_t ks2 = ks0 ^ ks1 ^ 0x1BD11BDAu;
  x0 += ks0; x1 += ks1;
#define TF_ROUND(r) { x0 += x1; x1 = (x1 << (r)) | (x1 >> (32 - (r))); x1 ^= x0; }
  TF_ROUND(13) TF_ROUND(15) TF_ROUND(26) TF_ROUND(6)
  x0 += ks1; x1 += ks2 + 1u;
  TF_ROUND(17) TF_ROUND(29) TF_ROUND(16) TF_ROUND(24)
  x0 += ks2; x1 += ks0 + 2u;
  TF_ROUND(13) TF_ROUND(15) TF_ROUND(26) TF_ROUND(6)
  x0 += ks0; x1 += ks1 + 3u;
  TF_ROUND(17) TF_ROUND(29) TF_ROUND(16) TF_ROUND(24)
  x0 += ks1; x1 += ks2 + 4u;
  TF_ROUND(13) TF_ROUND(15) TF_ROUND(26) TF_ROUND(6)
  x0 += ks2; x1 += ks0 + 5u;
#undef TF_ROUND
}

__device__ __forceinline__ unsigned short f2bf_rne(float f) {
  uint32_t u = __float_as_uint(f);
  uint32_t r = (u + 0x7fffu + ((u >> 16) & 1u)) >> 16;
  return (unsigned short)r;
}
__device__ __forceinline__ float bf2f(unsigned short h) {
  return __uint_as_float((uint32_t)h << 16);
}

// ---------------- row sum-of-squares ----------------
__global__ __launch_bounds__(256) void rownorm_kernel(const float* __restrict__ M,
                                                      float* __restrict__ out) {
  int lane = threadIdx.x & 63;
  int row = (int)((blockIdx.x * blockDim.x + threadIdx.x) >> 6);
  const float* p = M + (size_t)row * N_DIM;
  float acc = 0.f;
#pragma unroll
  for (int d = 0; d < N_DIM; d += 64) {
    float v = p[d + lane];
    acc = fmaf(v, v, acc);
  }
#pragma unroll
  for (int off = 32; off; off >>= 1) acc += __shfl_xor(acc, off, 64);
  if (lane == 0) out[row] = acc;
}

__global__ __launch_bounds__(256) void init_state_kernel(float* __restrict__ rmin,
                                                         int* __restrict__ ridx) {
  int i = blockIdx.x * 256 + threadIdx.x;
  if (i < N_ROWS * N_SAMP) { rmin[i] = INFINITY; ridx[i] = 0; }
}

// ---------------- bf16x2 split: fp32 (8192x512) -> bf16 (8192x1536) ----------------
// mode 0 (A/x):   zones [hi | lo | hi]
// mode 1 (B/emb): zones [hi | hi | lo]
__global__ __launch_bounds__(256) void split_kernel(const float* __restrict__ src,
                                                    unsigned short* __restrict__ dst,
                                                    int mode) {
  int t = blockIdx.x * 256 + threadIdx.x;       // N_ROWS * 128 threads
  int row = t >> 7;
  int c = (t & 127) << 2;
  float4 v = *(const float4*)(src + (size_t)row * N_DIM + c);
  ushort4 hi, lo;
  hi.x = f2bf_rne(v.x); lo.x = f2bf_rne(v.x - bf2f(hi.x));
  hi.y = f2bf_rne(v.y); lo.y = f2bf_rne(v.y - bf2f(hi.y));
  hi.z = f2bf_rne(v.z); lo.z = f2bf_rne(v.z - bf2f(hi.z));
  hi.w = f2bf_rne(v.w); lo.w = f2bf_rne(v.w - bf2f(hi.w));
  unsigned short* base = dst + (size_t)row * GK;
  *(ushort4*)(base + c) = hi;
  if (mode == 0) {
    *(ushort4*)(base + 512 + c) = lo;
    *(ushort4*)(base + 1024 + c) = hi;
  } else {
    *(ushort4*)(base + 512 + c) = hi;
    *(ushort4*)(base + 1024 + c) = lo;
  }
}

// ---------------- bf16 MFMA NT GEMM, async LDS staging (m97), E-epilogue ----------------
// E[i][j] = expf((xx[i] + ee[j] - 2*dot(a_i, b_j)) / 8192)
__device__ __forceinline__ void async_cp16(const void* g, void* l) {
  __builtin_amdgcn_global_load_lds((const __attribute__((address_space(1))) void*)g,
                                   (__attribute__((address_space(3))) void*)l, 16, 0, 0);
}

__global__ __launch_bounds__(256) void gemm_bf16_kernel(const unsigned short* __restrict__ A2,
                                                        const unsigned short* __restrict__ B2,
                                                        const float* __restrict__ xx,
                                                        const float* __restrict__ ee,
                                                        float* __restrict__ E,
                                                        int ks, int KC) {
  __shared__ __align__(16) unsigned short As[128 * 32];
  __shared__ __align__(16) unsigned short Bs[128 * 32];
  int tid = threadIdx.x;
  int w = tid >> 6, l = tid & 63;
  int row0 = blockIdx.y * 128;
  int col0 = blockIdx.x * 128;      // within-strip column
  int bcol0 = ks + col0;            // global token row of B2
  int wm = (w & 1) * 64, wn = (w >> 1) * 64;
  int quad = l >> 4, r15 = l & 15;

  f32x4_t acc[4][4];
#pragma unroll
  for (int i = 0; i < 4; ++i)
#pragma unroll
    for (int j = 0; j < 4; ++j) acc[i][j] = (f32x4_t){0.f, 0.f, 0.f, 0.f};

  // 512 x 16B chunks per 128x32 tile; lane-contiguous LDS dest (base + lane*16)
  int c0 = w * 64 + l;
  int c1 = c0 + 256;
  const size_t ga0 = (size_t)(row0 + (c0 >> 2)) * GK + (c0 & 3) * 8;
  const size_t ga1 = (size_t)(row0 + (c1 >> 2)) * GK + (c1 & 3) * 8;
  const size_t gb0 = (size_t)(bcol0 + (c0 >> 2)) * GK + (c0 & 3) * 8;
  const size_t gb1 = (size_t)(bcol0 + (c1 >> 2)) * GK + (c1 & 3) * 8;

  for (int k0 = 0; k0 < GK; k0 += 32) {
    async_cp16(A2 + ga0 + k0, As + c0 * 8);
    async_cp16(A2 + ga1 + k0, As + c1 * 8);
    async_cp16(B2 + gb0 + k0, Bs + c0 * 8);
    async_cp16(B2 + gb1 + k0, Bs + c1 * 8);
    __syncthreads();   // drains vmcnt (compiler emits waitcnt before s_barrier)

    bf16x8_t af[4], bf[4];
#pragma unroll
    for (int i = 0; i < 4; ++i)
      af[i] = *(const bf16x8_t*)&As[(wm + i * 16 + r15) * 32 + quad * 8];
#pragma unroll
    for (int j = 0; j < 4; ++j)
      bf[j] = *(const bf16x8_t*)&Bs[(wn + j * 16 + r15) * 32 + quad * 8];
#pragma unroll
    for (int i = 0; i < 4; ++i)
#pragma unroll
      for (int j = 0; j < 4; ++j)
        acc[i][j] = __builtin_amdgcn_mfma_f32_16x16x32_bf16(af[i], bf[j], acc[i][j], 0, 0, 0);
    __syncthreads();
  }

  // epilogue: C/D layout col=lane&15, row=(lane>>4)*4+reg; write E = expf(dists)
  const float inv_nt = 1.f / 8192.f;
  float eev[4];
#pragma unroll
  for (int j = 0; j < 4; ++j) eev[j] = ee[ks + col0 + wn + j * 16 + r15];
#pragma unroll
  for (int i = 0; i < 4; ++i) {
#pragma unroll
    for (int r = 0; r < 4; ++r) {
      int grow = row0 + wm + i * 16 + quad * 4 + r;
      float xxv = xx[grow];
#pragma unroll
      for (int j = 0; j < 4; ++j) {
        int gcol = col0 + wn + j * 16 + r15;
        float dist = (xxv + eev[j] - 2.0f * acc[i][j][r]) * inv_nt;
        E[(size_t)grow * KC + gcol] = expf(dist);
      }
    }
  }
}

// ---------------- fp32 NT GEMM (fallback path) with E-epilogue ----------------
__global__ __launch_bounds__(256) void gemm_nt_kernel(const float* __restrict__ A,
                                                      const float* __restrict__ B,
                                                      const float* __restrict__ xx,
                                                      const float* __restrict__ ee,
                                                      float* __restrict__ E,
                                                      int ks, int KC) {
  __shared__ __align__(16) float Asf[32][68];
  __shared__ __align__(16) float Bsf[32][68];
  int tid = threadIdx.x;
  int row0 = blockIdx.y * 64;
  int colB0 = blockIdx.x * 64 + ks;
  int tx = tid & 15, ty = tid >> 4;
  float acc[4][4] = {};
  for (int d0 = 0; d0 < N_DIM; d0 += 32) {
#pragma unroll
    for (int r = 0; r < 2; ++r) {
      int c = tid + 256 * r;
      int m = c >> 3;
      int dv = (c & 7) << 2;
      const float4 va = *(const float4*)(A + (size_t)(row0 + m) * N_DIM + d0 + dv);
      Asf[dv + 0][m] = va.x; Asf[dv + 1][m] = va.y;
      Asf[dv + 2][m] = va.z; Asf[dv + 3][m] = va.w;
      const float4 vb = *(const float4*)(B + (size_t)(colB0 + m) * N_DIM + d0 + dv);
      Bsf[dv + 0][m] = vb.x; Bsf[dv + 1][m] = vb.y;
      Bsf[dv + 2][m] = vb.z; Bsf[dv + 3][m] = vb.w;
    }
    __syncthreads();
#pragma unroll
    for (int dd = 0; dd < 32; ++dd) {
      float4 a4 = *(const float4*)&Asf[dd][ty << 2];
      float4 b4 = *(const float4*)&Bsf[dd][tx << 2];
      float av[4] = {a4.x, a4.y, a4.z, a4.w};
      float bv[4] = {b4.x, b4.y, b4.z, b4.w};
#pragma unroll
      for (int i = 0; i < 4; ++i)
#pragma unroll
        for (int j = 0; j < 4; ++j)
          acc[i][j] = fmaf(av[i], bv[j], acc[i][j]);
    }
    __syncthreads();
  }
  const float inv_nt = 1.f / 8192.f;
  int colC0 = blockIdx.x * 64;
  float eev[4];
#pragma unroll
  for (int j = 0; j < 4; ++j) eev[j] = ee[ks + colC0 + (tx << 2) + j];
#pragma unroll
  for (int i = 0; i < 4; ++i) {
    int grow = row0 + (ty << 2) + i;
    float xxv = xx[grow];
    float4 v;
    v.x = expf((xxv + eev[0] - 2.0f * acc[i][0]) * inv_nt);
    v.y = expf((xxv + eev[1] - 2.0f * acc[i][1]) * inv_nt);
    v.z = expf((xxv + eev[2] - 2.0f * acc[i][2]) * inv_nt);
    v.w = expf((xxv + eev[3] - 2.0f * acc[i][3]) * inv_nt);
    *(float4*)(E + (size_t)grow * KC + colC0 + (tx << 2)) = v;
  }
}

// ---------------- gumbel argmax sampling, single-log form ----------------
// argmax_k (g_k + L_k) == argmin_k (-log u_k) * exp(dists_k); E_k = exp(dists_k) precomputed.
__global__ __launch_bounds__(256) void sample_kernel(const float* __restrict__ E,
                                                     float* __restrict__ rmin,
                                                     int* __restrict__ ridx,
                                                     int ks, int KC,
                                                     uint32_t k0, uint32_t k1) {
  int lane = threadIdx.x & 63;
  int row = (int)((blockIdx.x * blockDim.x + threadIdx.x) >> 6);
  float bmin[N_SAMP];
  int bidx[N_SAMP];
#pragma unroll
  for (int s = 0; s < N_SAMP; ++s) { bmin[s] = INFINITY; bidx[s] = 0; }
  const float tiny = 1.1754943508222875e-38f;
  uint32_t row_c = (uint32_t)row * (uint32_t)N_SAMP * 8192u;

  for (int kk = lane; kk < KC; kk += 64) {
    int k = ks + kk;
    float Ek = E[(size_t)row * KC + kk];
    uint32_t base_c = row_c + (uint32_t)k;
#pragma unroll
    for (int s = 0; s < N_SAMP; ++s) {
      uint32_t x0 = 0u, x1 = base_c + (uint32_t)s * 8192u;
      tf2x32(k0, k1, x0, x1);
      uint32_t bits = x0 ^ x1;
      float u = __uint_as_float(0x3f800000u | (bits >> 9)) - 1.0f;
      u = fmaxf(u, tiny);                 // == reference's u+tiny;max(tiny,·) in fp32
      float wv = -logf(u) * Ek;           // ranking-equivalent to g + L
      if (wv < bmin[s]) { bmin[s] = wv; bidx[s] = k; }
    }
  }
  // wave arg-reduce: min value, ties -> smallest index
#pragma unroll
  for (int s = 0; s < N_SAMP; ++s) {
    float v = bmin[s];
    int id = bidx[s];
#pragma unroll
    for (int off = 32; off; off >>= 1) {
      float ov = __shfl_xor(v, off, 64);
      int oi = __shfl_xor(id, off, 64);
      if (ov < v || (ov == v && oi < id)) { v = ov; id = oi; }
    }
    if (lane == 0) {
      size_t p = (size_t)row * N_SAMP + s;
      if (v < rmin[p]) { rmin[p] = v; ridx[p] = id; }   // strips ascend in k
    }
  }
}

// ---------------- gather + mean + straight-through ----------------
__global__ __launch_bounds__(256) void gather_kernel(const float* __restrict__ emb,
                                                     const int* __restrict__ ridx,
                                                     const float* __restrict__ x,
                                                     float* __restrict__ outq,
                                                     float* __restrict__ outs) {
  int lane = threadIdx.x & 63;
  int row = (int)((blockIdx.x * blockDim.x + threadIdx.x) >> 6);
  int idx[N_SAMP];
#pragma unroll
  for (int s = 0; s < N_SAMP; ++s) idx[s] = ridx[row * N_SAMP + s];
  if (lane < N_SAMP) outs[row * N_SAMP + lane] = (float)idx[lane];
#pragma unroll
  for (int c = lane; c < N_DIM; c += 64) {
    float sum = 0.f;
#pragma unroll
    for (int s = 0; s < N_SAMP; ++s) sum += emb[(size_t)idx[s] * N_DIM + c];
    float qe = sum / 10.0f;
    float xv = x[(size_t)row * N_DIM + c];
    outq[(size_t)row * N_DIM + c] = xv + (qe - xv);
  }
}

extern "C" void kernel_launch(void* const* d_in, const int* in_sizes, int n_in,
                              void* d_out, int out_size, void* d_ws, size_t ws_size,
                              hipStream_t stream) {
  const float* x = (const float*)d_in[0];
  const float* emb = (const float*)d_in[1];
  float* out_q = (float*)d_out;
  float* out_s = out_q + (size_t)N_ROWS * N_DIM;

  const size_t fixed_f = (size_t)N_ROWS + N_TOK + 2 * (size_t)N_ROWS * N_SAMP;  // 180224 floats
  const size_t out_f = (size_t)N_ROWS * N_DIM + (size_t)N_ROWS * N_SAMP;
  const size_t split_u = (size_t)N_ROWS * GK;  // ushorts per split matrix

  // skey = fold_in(key(0), 1)
  uint32_t s0 = 0u, s1 = 1u;
  tf2x32(0u, 0u, s0, s1);

  // ---- preferred path: bf16x2 MFMA GEMM, needs fixed + 2 splits + E strip in ws ----
  int KC = 0;
  for (int c = 8192; c >= 128; c >>= 1) {
    size_t need = fixed_f * 4 + 2 * split_u * 2 + (size_t)N_ROWS * c * 4;
    if (need <= ws_size) { KC = c; break; }
  }

  if (KC) {
    float* xx = (float*)d_ws;
    float* ee = xx + N_ROWS;
    float* rmin = ee + N_TOK;
    int* ridx = (int*)(rmin + (size_t)N_ROWS * N_SAMP);
    unsigned short* A2 = (unsigned short*)(ridx + (size_t)N_ROWS * N_SAMP);
    unsigned short* B2 = A2 + split_u;
    float* E = (float*)(B2 + split_u);

    rownorm_kernel<<<2048, 256, 0, stream>>>(x, xx);
    rownorm_kernel<<<2048, 256, 0, stream>>>(emb, ee);
    init_state_kernel<<<(N_ROWS * N_SAMP + 255) / 256, 256, 0, stream>>>(rmin, ridx);
    split_kernel<<<N_ROWS * 128 / 256, 256, 0, stream>>>(x, A2, 0);
    split_kernel<<<N_ROWS * 128 / 256, 256, 0, stream>>>(emb, B2, 1);

    for (int ks = 0; ks < N_TOK; ks += KC) {
      gemm_bf16_kernel<<<dim3(KC / 128, N_ROWS / 128), 256, 0, stream>>>(A2, B2, xx, ee, E, ks, KC);
      sample_kernel<<<2048, 256, 0, stream>>>(E, rmin, ridx, ks, KC, s0, s1);
    }
    gather_kernel<<<2048, 256, 0, stream>>>(emb, ridx, x, out_q, out_s);
    return;
  }

  // ---- fallback: fp32 path with adaptive placement ----
  float *xx, *ee, *rmin, *E;
  int* ridx;
  KC = 0;
  for (int c = 8192; c >= 64; c >>= 1) {
    if ((fixed_f + (size_t)N_ROWS * c) * 4 <= ws_size) { KC = c; break; }
  }
  if (KC) {
    xx = (float*)d_ws;
    ee = xx + N_ROWS;
    rmin = ee + N_TOK;
    ridx = (int*)(rmin + (size_t)N_ROWS * N_SAMP);
    E = (float*)(ridx + (size_t)N_ROWS * N_SAMP);
  } else if (fixed_f * 4 <= ws_size) {
    KC = 512;
    xx = (float*)d_ws;
    ee = xx + N_ROWS;
    rmin = ee + N_TOK;
    ridx = (int*)(rmin + (size_t)N_ROWS * N_SAMP);
    E = out_q;
  } else {
    KC = 256;
    E = out_q;
    float* tail = out_q + (out_f - fixed_f);
    xx = tail;
    ee = xx + N_ROWS;
    rmin = ee + N_TOK;
    ridx = (int*)(rmin + (size_t)N_ROWS * N_SAMP);
  }

  rownorm_kernel<<<2048, 256, 0, stream>>>(x, xx);
  rownorm_kernel<<<2048, 256, 0, stream>>>(emb, ee);
  init_state_kernel<<<(N_ROWS * N_SAMP + 255) / 256, 256, 0, stream>>>(rmin, ridx);
  for (int ks = 0; ks < N_TOK; ks += KC) {
    gemm_nt_kernel<<<dim3(KC / 64, N_ROWS / 64), 256, 0, stream>>>(x, emb, xx, ee, E, ks, KC);
    sample_kernel<<<2048, 256, 0, stream>>>(E, rmin, ridx, ks, KC, s0, s1);
  }
  gather_kernel<<<2048, 256, 0, stream>>>(emb, ridx, x, out_q, out_s);
}